// Round 1
// baseline (2623.572 us; speedup 1.0000x reference)
//
#include <hip/hip_runtime.h>
#include <math.h>

#define NN   50000
#define TT   2
#define CC   768
#define GG   16
#define EE   800000
#define HH   192
#define OUTD 3
#define MR   (NN*TT)   // 100000 rows
#define FD   (TT*HH)   // 384 features per node
#define EPS_GN 1e-5f
#define GN_CHUNK 128

__device__ __forceinline__ float gelu_exact(float x){
    return 0.5f * x * (1.0f + erff(x * 0.70710678118654752440f));
}

// ---------- degree / counts ----------
__global__ __launch_bounds__(256) void k_deg(const int* __restrict__ dst, float* __restrict__ deg){
    int e = blockIdx.x*256 + threadIdx.x;
    if(e < EE) atomicAdd(&deg[dst[e]], 1.0f);
}

__global__ __launch_bounds__(256) void k_cnt(const int* __restrict__ batch, float* __restrict__ cnt){
    int i = blockIdx.x*256 + threadIdx.x;
    if(i < NN) atomicAdd(&cnt[batch[i]], 1.0f);
}

__global__ __launch_bounds__(256) void k_dinv(const float* __restrict__ deg, float* __restrict__ dinv){
    int i = blockIdx.x*256 + threadIdx.x;
    if(i < NN) dinv[i] = rsqrtf(deg[i] + 1.0f);   // deg holds edge count; +1 self loop
}

// ---------- CSR build: 3-stage exclusive scan over per-node edge counts ----------
__global__ __launch_bounds__(256) void k_scan1(const float* __restrict__ deg, int* __restrict__ partial){
    __shared__ int s[256];
    int t = threadIdx.x;
    int i = blockIdx.x*256 + t;
    int v = (i < NN) ? (int)deg[i] : 0;
    s[t] = v; __syncthreads();
    for(int off=128; off>0; off>>=1){ if(t < off) s[t] += s[t+off]; __syncthreads(); }
    if(t == 0) partial[blockIdx.x] = s[0];
}

__global__ __launch_bounds__(256) void k_scan2(int* __restrict__ partial){
    __shared__ int s[256];
    int t = threadIdx.x;
    int v = partial[t];           // zero-padded beyond #blocks
    s[t] = v; __syncthreads();
    for(int off=1; off<256; off<<=1){
        int x = (t >= off) ? s[t-off] : 0;
        __syncthreads();
        s[t] += x;
        __syncthreads();
    }
    partial[t] = s[t] - v;        // exclusive
}

__global__ __launch_bounds__(256) void k_scan3(const float* __restrict__ deg, const int* __restrict__ partial,
                                               int* __restrict__ csr_off){
    __shared__ int s[256];
    int t = threadIdx.x;
    int i = blockIdx.x*256 + t;
    int v = (i < NN) ? (int)deg[i] : 0;
    s[t] = v; __syncthreads();
    for(int off=1; off<256; off<<=1){
        int x = (t >= off) ? s[t-off] : 0;
        __syncthreads();
        s[t] += x;
        __syncthreads();
    }
    if(i < NN) csr_off[i] = partial[blockIdx.x] + s[t] - v;
}

__global__ __launch_bounds__(256) void k_fill(const int* __restrict__ src, const int* __restrict__ dst,
                                              const int* __restrict__ csr_off, int* __restrict__ fillcnt,
                                              int* __restrict__ csr_src){
    int e = blockIdx.x*256 + threadIdx.x;
    if(e < EE){
        int d = dst[e];
        int pos = csr_off[d] + atomicAdd(&fillcnt[d], 1);
        csr_src[pos] = src[e];
    }
}

// ---------- fp32 register-tiled GEMM: C[M][192] = A[M][K] * B[K][192] ----------
// block tile 64x64, BK=16, 256 threads, 4x4 micro-tile per thread
template<bool BIAS, bool GELU>
__global__ __launch_bounds__(256) void k_gemm(const float* __restrict__ A, const float* __restrict__ B,
                                              const float* __restrict__ bias, float* __restrict__ C,
                                              int Mrows, int Kdim){
    __shared__ float As[16][68];   // [k][m], pad 68 -> 16B-aligned float4 rows, 2-way-max bank
    __shared__ float Bs[16][64];   // [k][n]
    const int NCOL = HH;
    int tid = threadIdx.x;
    int bm = blockIdx.x*64, bn = blockIdx.y*64;
    int arow = tid>>2,  acol = (tid&3)<<2;    // A: 64 rows x 16 k, float4 per thread
    int brow = tid>>4,  bcol = (tid&15)<<2;   // B: 16 k x 64 n, float4 per thread
    bool aok = (bm + arow) < Mrows;
    const float* Ap = A + (size_t)(bm + arow)*Kdim + acol;
    const float* Bp = B + (size_t)brow*NCOL + bn + bcol;
    float acc[4][4] = {};
    int ty = tid>>4, tx = tid&15;
    for(int k0 = 0; k0 < Kdim; k0 += 16){
        float4 av = make_float4(0.f,0.f,0.f,0.f);
        if(aok) av = *(const float4*)(Ap + k0);
        float4 bv = *(const float4*)(Bp + (size_t)k0*NCOL);
        __syncthreads();
        As[acol+0][arow]=av.x; As[acol+1][arow]=av.y; As[acol+2][arow]=av.z; As[acol+3][arow]=av.w;
        *(float4*)&Bs[brow][bcol] = bv;
        __syncthreads();
        #pragma unroll
        for(int kk=0; kk<16; kk++){
            float4 a = *(const float4*)&As[kk][ty<<2];
            float4 b = *(const float4*)&Bs[kk][tx<<2];
            acc[0][0]+=a.x*b.x; acc[0][1]+=a.x*b.y; acc[0][2]+=a.x*b.z; acc[0][3]+=a.x*b.w;
            acc[1][0]+=a.y*b.x; acc[1][1]+=a.y*b.y; acc[1][2]+=a.y*b.z; acc[1][3]+=a.y*b.w;
            acc[2][0]+=a.z*b.x; acc[2][1]+=a.z*b.y; acc[2][2]+=a.z*b.z; acc[2][3]+=a.z*b.w;
            acc[3][0]+=a.w*b.x; acc[3][1]+=a.w*b.y; acc[3][2]+=a.w*b.z; acc[3][3]+=a.w*b.w;
        }
    }
    #pragma unroll
    for(int i=0;i<4;i++){
        int r = bm + (ty<<2) + i;
        if(r < Mrows){
            float4 o;
            float* po = (float*)&o;
            #pragma unroll
            for(int j=0;j<4;j++){
                float v = acc[i][j];
                if(BIAS) v += bias[bn + (tx<<2) + j];
                if(GELU) v = gelu_exact(v);
                po[j] = v;
            }
            *(float4*)&C[(size_t)r*NCOL + bn + (tx<<2)] = o;
        }
    }
}

// ---------- GCN aggregation via CSR (no atomics): one block per dst node ----------
__global__ __launch_bounds__(384) void k_agg(const float* __restrict__ hw, const int* __restrict__ csr_src,
                                             const int* __restrict__ csr_off, const float* __restrict__ deg,
                                             const float* __restrict__ dinv, const float* __restrict__ bias,
                                             float* __restrict__ out){
    int n = blockIdx.x;
    int f = threadIdx.x;           // 0..383 = t*192 + h
    float di = dinv[n];
    float acc = hw[(size_t)n*FD + f] * (di*di);   // self loop
    int beg = csr_off[n];
    int end = beg + (int)deg[n];
    for(int p = beg; p < end; p++){
        int s = csr_src[p];
        float nr = dinv[s] * di;
        acc += hw[(size_t)s*FD + f] * nr;
    }
    int hh = (f < HH) ? f : f - HH;
    out[(size_t)n*FD + f] = acc + bias[hh];
}

// ---------- GraphNorm (batch is sorted -> run-compressed atomics) ----------
__global__ __launch_bounds__(384) void k_gn_sum(const float* __restrict__ h, const int* __restrict__ batch,
                                                float* __restrict__ stats){
    int f = threadIdx.x;
    int n0 = blockIdx.x*GN_CHUNK;
    int n1 = min(n0 + GN_CHUNK, NN);
    int g = batch[n0];
    float acc = 0.f;
    for(int n = n0; n < n1; n++){
        int gn = batch[n];
        if(gn != g){ atomicAdd(&stats[g*FD + f], acc); acc = 0.f; g = gn; }
        acc += h[(size_t)n*FD + f];
    }
    atomicAdd(&stats[g*FD + f], acc);
}

__global__ __launch_bounds__(384) void k_gn_center(float* __restrict__ h, const int* __restrict__ batch,
                                                   const float* __restrict__ stats_m, const float* __restrict__ cnt,
                                                   const float* __restrict__ alpha, float* __restrict__ stats_v){
    int f = threadIdx.x;
    int hh = (f < HH) ? f : f - HH;
    float a = alpha[hh];
    int n0 = blockIdx.x*GN_CHUNK;
    int n1 = min(n0 + GN_CHUNK, NN);
    int g = batch[n0];
    float mean = stats_m[g*FD + f] / cnt[g];
    float acc = 0.f;
    for(int n = n0; n < n1; n++){
        int gn = batch[n];
        if(gn != g){
            atomicAdd(&stats_v[g*FD + f], acc); acc = 0.f; g = gn;
            mean = stats_m[g*FD + f] / cnt[g];
        }
        float o = h[(size_t)n*FD + f] - a*mean;
        h[(size_t)n*FD + f] = o;
        acc += o*o;
    }
    atomicAdd(&stats_v[g*FD + f], acc);
}

__global__ __launch_bounds__(384) void k_gn_final(const float* __restrict__ h, const int* __restrict__ batch,
                                                  const float* __restrict__ stats_v, const float* __restrict__ cnt,
                                                  const float* __restrict__ w, const float* __restrict__ b,
                                                  const float* __restrict__ res, float* __restrict__ out){
    int n = blockIdx.x;
    int f = threadIdx.x;
    int hh = (f < HH) ? f : f - HH;
    int g = batch[n];
    float var = stats_v[g*FD + f] / cnt[g];
    float o = h[(size_t)n*FD + f];
    float v = w[hh]*o*rsqrtf(var + EPS_GN) + b[hh];
    v = gelu_exact(v);
    if(res) v += res[(size_t)n*FD + f];
    out[(size_t)n*FD + f] = v;
}

// ---------- head: [M,192] @ [192,3] + b, one wave per row ----------
__global__ __launch_bounds__(256) void k_head2(const float* __restrict__ h, const float* __restrict__ W,
                                               const float* __restrict__ bias, float* __restrict__ out){
    int wave = threadIdx.x >> 6;
    int lane = threadIdx.x & 63;
    int r = blockIdx.x*4 + wave;
    if(r >= MR) return;
    const float* hp = h + (size_t)r*HH;
    float a0=0.f, a1=0.f, a2=0.f;
    for(int k = lane; k < HH; k += 64){
        float v = hp[k];
        a0 += v*W[k*3+0]; a1 += v*W[k*3+1]; a2 += v*W[k*3+2];
    }
    #pragma unroll
    for(int off=32; off; off>>=1){
        a0 += __shfl_down(a0, off);
        a1 += __shfl_down(a1, off);
        a2 += __shfl_down(a2, off);
    }
    if(lane == 0){
        out[(size_t)r*3+0] = a0 + bias[0];
        out[(size_t)r*3+1] = a1 + bias[1];
        out[(size_t)r*3+2] = a2 + bias[2];
    }
}

extern "C" void kernel_launch(void* const* d_in, const int* in_sizes, int n_in,
                              void* d_out, int out_size, void* d_ws, size_t ws_size,
                              hipStream_t stream){
    const float* x     = (const float*)d_in[0];
    const int*   batch = (const int*)d_in[1];
    const int*   ei    = (const int*)d_in[2];
    const int*   src   = ei;
    const int*   dst   = ei + EE;
    const float* W0    = (const float*)d_in[3];
    const float* b0    = (const float*)d_in[4];
    const float* gn0_w = (const float*)d_in[5];
    const float* gn0_b = (const float*)d_in[6];
    const float* gn0_a = (const float*)d_in[7];
    const float* W1    = (const float*)d_in[8];
    const float* b1    = (const float*)d_in[9];
    const float* gn1_w = (const float*)d_in[10];
    const float* gn1_b = (const float*)d_in[11];
    const float* gn1_a = (const float*)d_in[12];
    const float* Wh1   = (const float*)d_in[13];
    const float* bh1   = (const float*)d_in[14];
    const float* Wh2   = (const float*)d_in[15];
    const float* bh2   = (const float*)d_in[16];
    float* out = (float*)d_out;

    char* w = (char*)d_ws;
    auto alloc = [&](size_t bytes)->void*{
        void* p = (void*)w;
        w += (bytes + 255) & ~(size_t)255;
        return p;
    };
    // zeroed region (single memset)
    char* zbase = w;
    float* deg     = (float*)alloc((size_t)NN*4);
    float* cnt     = (float*)alloc((size_t)GG*4);
    int*   fillcnt = (int*)  alloc((size_t)NN*4);
    int*   partial = (int*)  alloc(256*4);
    float* st0m    = (float*)alloc((size_t)GG*FD*4);
    float* st0v    = (float*)alloc((size_t)GG*FD*4);
    float* st1m    = (float*)alloc((size_t)GG*FD*4);
    float* st1v    = (float*)alloc((size_t)GG*FD*4);
    size_t zbytes = (size_t)(w - zbase);
    float* dinv    = (float*)alloc((size_t)NN*4);
    int*   csr_off = (int*)  alloc((size_t)NN*4);
    int*   csr_src = (int*)  alloc((size_t)EE*4);
    float* bufA    = (float*)alloc((size_t)MR*HH*4);
    float* bufB    = (float*)alloc((size_t)MR*HH*4);
    float* bufC    = (float*)alloc((size_t)MR*HH*4);

    hipMemsetAsync(zbase, 0, zbytes, stream);

    k_deg <<<(EE+255)/256, 256, 0, stream>>>(dst, deg);
    k_cnt <<<(NN+255)/256, 256, 0, stream>>>(batch, cnt);
    k_dinv<<<(NN+255)/256, 256, 0, stream>>>(deg, dinv);

    int nscan = (NN+255)/256;   // 196 <= 256
    k_scan1<<<nscan, 256, 0, stream>>>(deg, partial);
    k_scan2<<<1,     256, 0, stream>>>(partial);
    k_scan3<<<nscan, 256, 0, stream>>>(deg, partial, csr_off);
    k_fill <<<(EE+255)/256, 256, 0, stream>>>(src, dst, csr_off, fillcnt, csr_src);

    dim3 gemm_grid((MR+63)/64, HH/64);
    int ngn = (NN + GN_CHUNK - 1)/GN_CHUNK;

    // layer 0: 768 -> 192
    k_gemm<false,false><<<gemm_grid, 256, 0, stream>>>(x, W0, nullptr, bufA, MR, CC);
    k_agg<<<NN, 384, 0, stream>>>(bufA, csr_src, csr_off, deg, dinv, b0, bufB);
    k_gn_sum   <<<ngn, 384, 0, stream>>>(bufB, batch, st0m);
    k_gn_center<<<ngn, 384, 0, stream>>>(bufB, batch, st0m, cnt, gn0_a, st0v);
    k_gn_final <<<NN,  384, 0, stream>>>(bufB, batch, st0v, cnt, gn0_w, gn0_b, nullptr, bufB);

    // layer 1: 192 -> 192 + residual
    k_gemm<false,false><<<gemm_grid, 256, 0, stream>>>(bufB, W1, nullptr, bufA, MR, HH);
    k_agg<<<NN, 384, 0, stream>>>(bufA, csr_src, csr_off, deg, dinv, b1, bufC);
    k_gn_sum   <<<ngn, 384, 0, stream>>>(bufC, batch, st1m);
    k_gn_center<<<ngn, 384, 0, stream>>>(bufC, batch, st1m, cnt, gn1_a, st1v);
    k_gn_final <<<NN,  384, 0, stream>>>(bufC, batch, st1v, cnt, gn1_w, gn1_b, bufB, bufB);

    // head
    k_gemm<true,true><<<gemm_grid, 256, 0, stream>>>(bufB, Wh1, bh1, bufA, MR, HH);
    k_head2<<<(MR+3)/4, 256, 0, stream>>>(bufA, Wh2, bh2, out);
}

// Round 2
// 1622.800 us; speedup vs baseline: 1.6167x; 1.6167x over previous
//
#include <hip/hip_runtime.h>
#include <math.h>

#define NN   50000
#define TT   2
#define CC   768
#define GG   16
#define EE   800000
#define HH   192
#define OUTD 3
#define MR   (NN*TT)   // 100000 rows
#define FD   (TT*HH)   // 384 features per node
#define EPS_GN 1e-5f
#define GN_CHUNK 128

typedef __attribute__((ext_vector_type(8))) short bf16x8;
typedef __attribute__((ext_vector_type(4))) float f32x4;

__device__ __forceinline__ float gelu_exact(float x){
    return 0.5f * x * (1.0f + erff(x * 0.70710678118654752440f));
}

__device__ __forceinline__ short f2b(float f){   // RNE float->bf16
    unsigned u = __float_as_uint(f);
    unsigned r = (u + 0x7FFFu + ((u>>16)&1u)) >> 16;
    return (short)r;
}

// ---------- degree / counts ----------
__global__ __launch_bounds__(256) void k_deg(const int* __restrict__ dst, float* __restrict__ deg){
    int e = blockIdx.x*256 + threadIdx.x;
    if(e < EE) atomicAdd(&deg[dst[e]], 1.0f);
}

// batch is sorted: cnt[g] via binary search, no atomics
__global__ __launch_bounds__(64) void k_cnt2(const int* __restrict__ batch, float* __restrict__ cnt){
    int g = threadIdx.x;
    if(g >= GG) return;
    int lo0=0, hi=NN;
    while(lo0<hi){ int mid=(lo0+hi)>>1; if(batch[mid] < g) lo0=mid+1; else hi=mid; }
    int lo1=lo0; hi=NN;
    while(lo1<hi){ int mid=(lo1+hi)>>1; if(batch[mid] < g+1) lo1=mid+1; else hi=mid; }
    cnt[g] = (float)(lo1 - lo0);
}

__global__ __launch_bounds__(256) void k_dinv(const float* __restrict__ deg, float* __restrict__ dinv){
    int i = blockIdx.x*256 + threadIdx.x;
    if(i < NN) dinv[i] = rsqrtf(deg[i] + 1.0f);
}

// ---------- weight convert: W[K][192] fp32 -> Wt[192][K] bf16 ----------
__global__ __launch_bounds__(256) void k_wconv(const float* __restrict__ W0, const float* __restrict__ W1,
                                               const float* __restrict__ Wh1,
                                               short* __restrict__ Wt0, short* __restrict__ Wt1,
                                               short* __restrict__ Wth1){
    int i = blockIdx.x*256 + threadIdx.x;
    if(i < CC*HH){
        int k = i / HH, n = i % HH;
        Wt0[(size_t)n*CC + k] = f2b(W0[i]);
    }
    if(i < HH*HH){
        int k = i / HH, n = i % HH;
        Wt1 [(size_t)n*HH + k] = f2b(W1[i]);
        Wth1[(size_t)n*HH + k] = f2b(Wh1[i]);
    }
}

// ---------- CSR build ----------
__global__ __launch_bounds__(256) void k_scan1(const float* __restrict__ deg, int* __restrict__ partial){
    __shared__ int s[256];
    int t = threadIdx.x;
    int i = blockIdx.x*256 + t;
    int v = (i < NN) ? (int)deg[i] : 0;
    s[t] = v; __syncthreads();
    for(int off=128; off>0; off>>=1){ if(t < off) s[t] += s[t+off]; __syncthreads(); }
    if(t == 0) partial[blockIdx.x] = s[0];
}

__global__ __launch_bounds__(256) void k_scan2(int* __restrict__ partial){
    __shared__ int s[256];
    int t = threadIdx.x;
    int v = partial[t];
    s[t] = v; __syncthreads();
    for(int off=1; off<256; off<<=1){
        int x = (t >= off) ? s[t-off] : 0;
        __syncthreads();
        s[t] += x;
        __syncthreads();
    }
    partial[t] = s[t] - v;
}

__global__ __launch_bounds__(256) void k_scan3(const float* __restrict__ deg, const int* __restrict__ partial,
                                               int* __restrict__ csr_off){
    __shared__ int s[256];
    int t = threadIdx.x;
    int i = blockIdx.x*256 + t;
    int v = (i < NN) ? (int)deg[i] : 0;
    s[t] = v; __syncthreads();
    for(int off=1; off<256; off<<=1){
        int x = (t >= off) ? s[t-off] : 0;
        __syncthreads();
        s[t] += x;
        __syncthreads();
    }
    if(i < NN) csr_off[i] = partial[blockIdx.x] + s[t] - v;
}

__global__ __launch_bounds__(256) void k_fill(const int* __restrict__ src, const int* __restrict__ dst,
                                              const int* __restrict__ csr_off, int* __restrict__ fillcnt,
                                              int* __restrict__ csr_src){
    int e = blockIdx.x*256 + threadIdx.x;
    if(e < EE){
        int d = dst[e];
        int pos = csr_off[d] + atomicAdd(&fillcnt[d], 1);
        csr_src[pos] = src[e];
    }
}

// ---------- bf16 MFMA GEMM: C[M][192] = A[M][K](fp32) * Bt[192][K](bf16) ----------
// BM=64, BN=192 (full width), BK=32, 256 threads = 4 waves, wave owns 16 rows x 192 cols
template<bool BIAS, bool GELU>
__global__ __launch_bounds__(256) void k_gemm_mfma(const float* __restrict__ A, const short* __restrict__ Bt,
                                                   const float* __restrict__ bias, float* __restrict__ C,
                                                   int Mrows, int Kdim){
    __shared__ short As[64][40];    // [m][k], pad 40 -> 2-way max bank aliasing on b128
    __shared__ short Bs[192][40];   // [n][k]
    int tid = threadIdx.x;
    int bm = blockIdx.x*64;
    int wv = tid>>6, lane = tid&63;
    int lm = lane&15, lq = lane>>4;

    f32x4 acc[12];
    #pragma unroll
    for(int i=0;i<12;i++) acc[i] = (f32x4){0.f,0.f,0.f,0.f};

    // A staging: thread t -> row t>>2, k-group (t&3)*8 (8 fp32 -> 8 bf16)
    int ar = tid>>2, akg = (tid&3)<<3;
    bool aok = (bm + ar) < Mrows;
    const float* Ap = A + (size_t)(bm + ar)*Kdim + akg;

    for(int k0 = 0; k0 < Kdim; k0 += 32){
        float4 av0 = make_float4(0.f,0.f,0.f,0.f), av1 = av0;
        if(aok){
            av0 = *(const float4*)(Ap + k0);
            av1 = *(const float4*)(Ap + k0 + 4);
        }
        bf16x8 bvals[3];
        #pragma unroll
        for(int i=0;i<3;i++){
            int idx = tid + i*256;         // 0..767
            int n = idx>>2, kg = (idx&3)<<3;
            bvals[i] = *(const bf16x8*)(Bt + (size_t)n*Kdim + k0 + kg);
        }
        __syncthreads();
        bf16x8 ap;
        ap[0]=f2b(av0.x); ap[1]=f2b(av0.y); ap[2]=f2b(av0.z); ap[3]=f2b(av0.w);
        ap[4]=f2b(av1.x); ap[5]=f2b(av1.y); ap[6]=f2b(av1.z); ap[7]=f2b(av1.w);
        *(bf16x8*)&As[ar][akg] = ap;
        #pragma unroll
        for(int i=0;i<3;i++){
            int idx = tid + i*256;
            int n = idx>>2, kg = (idx&3)<<3;
            *(bf16x8*)&Bs[n][kg] = bvals[i];
        }
        __syncthreads();
        bf16x8 af = *(const bf16x8*)&As[wv*16 + lm][lq*8];
        #pragma unroll
        for(int ct=0; ct<12; ct++){
            bf16x8 bf = *(const bf16x8*)&Bs[ct*16 + lm][lq*8];
            acc[ct] = __builtin_amdgcn_mfma_f32_16x16x32_bf16(af, bf, acc[ct], 0, 0, 0);
        }
    }
    // epilogue: C/D layout col=lane&15, row=lq*4+reg
    #pragma unroll
    for(int ct=0; ct<12; ct++){
        int col = ct*16 + lm;
        float bs = BIAS ? bias[col] : 0.f;
        #pragma unroll
        for(int r=0; r<4; r++){
            int row = bm + wv*16 + lq*4 + r;
            if(row < Mrows){
                float v = acc[ct][r] + bs;
                if(GELU) v = gelu_exact(v);
                C[(size_t)row*HH + col] = v;
            }
        }
    }
}

// ---------- GCN aggregation via CSR (no atomics) ----------
__global__ __launch_bounds__(384) void k_agg(const float* __restrict__ hw, const int* __restrict__ csr_src,
                                             const int* __restrict__ csr_off, const float* __restrict__ deg,
                                             const float* __restrict__ dinv, const float* __restrict__ bias,
                                             float* __restrict__ out){
    int n = blockIdx.x;
    int f = threadIdx.x;
    float di = dinv[n];
    float acc = hw[(size_t)n*FD + f] * (di*di);
    int beg = csr_off[n];
    int end = beg + (int)deg[n];
    for(int p = beg; p < end; p++){
        int s = csr_src[p];
        float nr = dinv[s] * di;
        acc += hw[(size_t)s*FD + f] * nr;
    }
    int hh = (f < HH) ? f : f - HH;
    out[(size_t)n*FD + f] = acc + bias[hh];
}

// ---------- GraphNorm ----------
__global__ __launch_bounds__(384) void k_gn_sum(const float* __restrict__ h, const int* __restrict__ batch,
                                                float* __restrict__ stats){
    int f = threadIdx.x;
    int n0 = blockIdx.x*GN_CHUNK;
    int n1 = min(n0 + GN_CHUNK, NN);
    int g = batch[n0];
    float acc = 0.f;
    for(int n = n0; n < n1; n++){
        int gn = batch[n];
        if(gn != g){ atomicAdd(&stats[g*FD + f], acc); acc = 0.f; g = gn; }
        acc += h[(size_t)n*FD + f];
    }
    atomicAdd(&stats[g*FD + f], acc);
}

__global__ __launch_bounds__(384) void k_gn_center(float* __restrict__ h, const int* __restrict__ batch,
                                                   const float* __restrict__ stats_m, const float* __restrict__ cnt,
                                                   const float* __restrict__ alpha, float* __restrict__ stats_v){
    int f = threadIdx.x;
    int hh = (f < HH) ? f : f - HH;
    float a = alpha[hh];
    int n0 = blockIdx.x*GN_CHUNK;
    int n1 = min(n0 + GN_CHUNK, NN);
    int g = batch[n0];
    float mean = stats_m[g*FD + f] / cnt[g];
    float acc = 0.f;
    for(int n = n0; n < n1; n++){
        int gn = batch[n];
        if(gn != g){
            atomicAdd(&stats_v[g*FD + f], acc); acc = 0.f; g = gn;
            mean = stats_m[g*FD + f] / cnt[g];
        }
        float o = h[(size_t)n*FD + f] - a*mean;
        h[(size_t)n*FD + f] = o;
        acc += o*o;
    }
    atomicAdd(&stats_v[g*FD + f], acc);
}

__global__ __launch_bounds__(384) void k_gn_final(const float* __restrict__ h, const int* __restrict__ batch,
                                                  const float* __restrict__ stats_v, const float* __restrict__ cnt,
                                                  const float* __restrict__ w, const float* __restrict__ b,
                                                  const float* __restrict__ res, float* __restrict__ out){
    int n = blockIdx.x;
    int f = threadIdx.x;
    int hh = (f < HH) ? f : f - HH;
    int g = batch[n];
    float var = stats_v[g*FD + f] / cnt[g];
    float o = h[(size_t)n*FD + f];
    float v = w[hh]*o*rsqrtf(var + EPS_GN) + b[hh];
    v = gelu_exact(v);
    if(res) v += res[(size_t)n*FD + f];
    out[(size_t)n*FD + f] = v;
}

// ---------- head: [M,192] @ [192,3] + b ----------
__global__ __launch_bounds__(256) void k_head2(const float* __restrict__ h, const float* __restrict__ W,
                                               const float* __restrict__ bias, float* __restrict__ out){
    int wave = threadIdx.x >> 6;
    int lane = threadIdx.x & 63;
    int r = blockIdx.x*4 + wave;
    if(r >= MR) return;
    const float* hp = h + (size_t)r*HH;
    float a0=0.f, a1=0.f, a2=0.f;
    for(int k = lane; k < HH; k += 64){
        float v = hp[k];
        a0 += v*W[k*3+0]; a1 += v*W[k*3+1]; a2 += v*W[k*3+2];
    }
    #pragma unroll
    for(int off=32; off; off>>=1){
        a0 += __shfl_down(a0, off);
        a1 += __shfl_down(a1, off);
        a2 += __shfl_down(a2, off);
    }
    if(lane == 0){
        out[(size_t)r*3+0] = a0 + bias[0];
        out[(size_t)r*3+1] = a1 + bias[1];
        out[(size_t)r*3+2] = a2 + bias[2];
    }
}

extern "C" void kernel_launch(void* const* d_in, const int* in_sizes, int n_in,
                              void* d_out, int out_size, void* d_ws, size_t ws_size,
                              hipStream_t stream){
    const float* x     = (const float*)d_in[0];
    const int*   batch = (const int*)d_in[1];
    const int*   ei    = (const int*)d_in[2];
    const int*   src   = ei;
    const int*   dst   = ei + EE;
    const float* W0    = (const float*)d_in[3];
    const float* b0    = (const float*)d_in[4];
    const float* gn0_w = (const float*)d_in[5];
    const float* gn0_b = (const float*)d_in[6];
    const float* gn0_a = (const float*)d_in[7];
    const float* W1    = (const float*)d_in[8];
    const float* b1    = (const float*)d_in[9];
    const float* gn1_w = (const float*)d_in[10];
    const float* gn1_b = (const float*)d_in[11];
    const float* gn1_a = (const float*)d_in[12];
    const float* Wh1   = (const float*)d_in[13];
    const float* bh1   = (const float*)d_in[14];
    const float* Wh2   = (const float*)d_in[15];
    const float* bh2   = (const float*)d_in[16];
    float* out = (float*)d_out;

    char* w = (char*)d_ws;
    auto alloc = [&](size_t bytes)->void*{
        void* p = (void*)w;
        w += (bytes + 255) & ~(size_t)255;
        return p;
    };
    char* zbase = w;
    float* deg     = (float*)alloc((size_t)NN*4);
    int*   fillcnt = (int*)  alloc((size_t)NN*4);
    int*   partial = (int*)  alloc(256*4);
    float* st0m    = (float*)alloc((size_t)GG*FD*4);
    float* st0v    = (float*)alloc((size_t)GG*FD*4);
    float* st1m    = (float*)alloc((size_t)GG*FD*4);
    float* st1v    = (float*)alloc((size_t)GG*FD*4);
    size_t zbytes = (size_t)(w - zbase);
    float* cnt     = (float*)alloc((size_t)GG*4);
    float* dinv    = (float*)alloc((size_t)NN*4);
    int*   csr_off = (int*)  alloc((size_t)NN*4);
    int*   csr_src = (int*)  alloc((size_t)EE*4);
    short* Wt0     = (short*)alloc((size_t)HH*CC*2);
    short* Wt1     = (short*)alloc((size_t)HH*HH*2);
    short* Wth1    = (short*)alloc((size_t)HH*HH*2);
    float* bufA    = (float*)alloc((size_t)MR*HH*4);
    float* bufB    = (float*)alloc((size_t)MR*HH*4);
    float* bufC    = (float*)alloc((size_t)MR*HH*4);

    hipMemsetAsync(zbase, 0, zbytes, stream);

    k_deg  <<<(EE+255)/256, 256, 0, stream>>>(dst, deg);
    k_cnt2 <<<1, 64, 0, stream>>>(batch, cnt);
    k_dinv <<<(NN+255)/256, 256, 0, stream>>>(deg, dinv);
    k_wconv<<<(CC*HH+255)/256, 256, 0, stream>>>(W0, W1, Wh1, Wt0, Wt1, Wth1);

    int nscan = (NN+255)/256;
    k_scan1<<<nscan, 256, 0, stream>>>(deg, partial);
    k_scan2<<<1,     256, 0, stream>>>(partial);
    k_scan3<<<nscan, 256, 0, stream>>>(deg, partial, csr_off);
    k_fill <<<(EE+255)/256, 256, 0, stream>>>(src, dst, csr_off, fillcnt, csr_src);

    int gemm_grid = (MR+63)/64;
    int ngn = (NN + GN_CHUNK - 1)/GN_CHUNK;

    // layer 0: 768 -> 192
    k_gemm_mfma<false,false><<<gemm_grid, 256, 0, stream>>>(x, Wt0, nullptr, bufA, MR, CC);
    k_agg<<<NN, 384, 0, stream>>>(bufA, csr_src, csr_off, deg, dinv, b0, bufB);
    k_gn_sum   <<<ngn, 384, 0, stream>>>(bufB, batch, st0m);
    k_gn_center<<<ngn, 384, 0, stream>>>(bufB, batch, st0m, cnt, gn0_a, st0v);
    k_gn_final <<<NN,  384, 0, stream>>>(bufB, batch, st0v, cnt, gn0_w, gn0_b, nullptr, bufB);

    // layer 1: 192 -> 192 + residual
    k_gemm_mfma<false,false><<<gemm_grid, 256, 0, stream>>>(bufB, Wt1, nullptr, bufA, MR, HH);
    k_agg<<<NN, 384, 0, stream>>>(bufA, csr_src, csr_off, deg, dinv, b1, bufC);
    k_gn_sum   <<<ngn, 384, 0, stream>>>(bufC, batch, st1m);
    k_gn_center<<<ngn, 384, 0, stream>>>(bufC, batch, st1m, cnt, gn1_a, st1v);
    k_gn_final <<<NN,  384, 0, stream>>>(bufC, batch, st1v, cnt, gn1_w, gn1_b, bufB, bufB);

    // head
    k_gemm_mfma<true,true><<<gemm_grid, 256, 0, stream>>>(bufB, Wth1, bh1, bufA, MR, HH);
    k_head2<<<(MR+3)/4, 256, 0, stream>>>(bufA, Wh2, bh2, out);
}

// Round 3
// 1054.068 us; speedup vs baseline: 2.4890x; 1.5396x over previous
//
#include <hip/hip_runtime.h>
#include <math.h>

#define NN   50000
#define TT   2
#define CC   768
#define GG   16
#define EE   800000
#define HH   192
#define OUTD 3
#define MR   (NN*TT)   // 100000 rows
#define FD   (TT*HH)   // 384 features per node
#define EPS_GN 1e-5f
#define GN_CHUNK 128
#define AGG_CH 128

typedef __attribute__((ext_vector_type(8))) short bf16x8;
typedef __attribute__((ext_vector_type(4))) float f32x4;

__device__ __forceinline__ float gelu_exact(float x){
    return 0.5f * x * (1.0f + erff(x * 0.70710678118654752440f));
}

__device__ __forceinline__ short f2b(float f){   // RNE float->bf16
    unsigned u = __float_as_uint(f);
    unsigned r = (u + 0x7FFFu + ((u>>16)&1u)) >> 16;
    return (short)r;
}
__device__ __forceinline__ float b2f(unsigned short u){
    return __uint_as_float(((unsigned)u)<<16);
}

// ---------- degree / counts ----------
__global__ __launch_bounds__(256) void k_deg(const int* __restrict__ dst, float* __restrict__ deg){
    int e = blockIdx.x*256 + threadIdx.x;
    if(e < EE) atomicAdd(&deg[dst[e]], 1.0f);
}

__global__ __launch_bounds__(64) void k_cnt2(const int* __restrict__ batch, float* __restrict__ cnt){
    int g = threadIdx.x;
    if(g >= GG) return;
    int lo0=0, hi=NN;
    while(lo0<hi){ int mid=(lo0+hi)>>1; if(batch[mid] < g) lo0=mid+1; else hi=mid; }
    int lo1=lo0; hi=NN;
    while(lo1<hi){ int mid=(lo1+hi)>>1; if(batch[mid] < g+1) lo1=mid+1; else hi=mid; }
    cnt[g] = (float)(lo1 - lo0);
}

__global__ __launch_bounds__(256) void k_dinv(const float* __restrict__ deg, float* __restrict__ dinv){
    int i = blockIdx.x*256 + threadIdx.x;
    if(i < NN) dinv[i] = rsqrtf(deg[i] + 1.0f);
}

// ---------- weight convert: W[K][192] fp32 -> Wt[192][K] bf16 ----------
__global__ __launch_bounds__(256) void k_wconv(const float* __restrict__ W0, const float* __restrict__ W1,
                                               const float* __restrict__ Wh1,
                                               short* __restrict__ Wt0, short* __restrict__ Wt1,
                                               short* __restrict__ Wth1){
    int i = blockIdx.x*256 + threadIdx.x;
    if(i < CC*HH){
        int k = i / HH, n = i % HH;
        Wt0[(size_t)n*CC + k] = f2b(W0[i]);
    }
    if(i < HH*HH){
        int k = i / HH, n = i % HH;
        Wt1 [(size_t)n*HH + k] = f2b(W1[i]);
        Wth1[(size_t)n*HH + k] = f2b(Wh1[i]);
    }
}

// ---------- CSR build ----------
__global__ __launch_bounds__(256) void k_scan1(const float* __restrict__ deg, int* __restrict__ partial){
    __shared__ int s[256];
    int t = threadIdx.x;
    int i = blockIdx.x*256 + t;
    int v = (i < NN) ? (int)deg[i] : 0;
    s[t] = v; __syncthreads();
    for(int off=128; off>0; off>>=1){ if(t < off) s[t] += s[t+off]; __syncthreads(); }
    if(t == 0) partial[blockIdx.x] = s[0];
}

__global__ __launch_bounds__(256) void k_scan2(int* __restrict__ partial){
    __shared__ int s[256];
    int t = threadIdx.x;
    int v = partial[t];
    s[t] = v; __syncthreads();
    for(int off=1; off<256; off<<=1){
        int x = (t >= off) ? s[t-off] : 0;
        __syncthreads();
        s[t] += x;
        __syncthreads();
    }
    partial[t] = s[t] - v;
}

__global__ __launch_bounds__(256) void k_scan3(const float* __restrict__ deg, const int* __restrict__ partial,
                                               int* __restrict__ csr_off){
    __shared__ int s[256];
    int t = threadIdx.x;
    int i = blockIdx.x*256 + t;
    int v = (i < NN) ? (int)deg[i] : 0;
    s[t] = v; __syncthreads();
    for(int off=1; off<256; off<<=1){
        int x = (t >= off) ? s[t-off] : 0;
        __syncthreads();
        s[t] += x;
        __syncthreads();
    }
    if(i < NN) csr_off[i] = partial[blockIdx.x] + s[t] - v;
}

__global__ __launch_bounds__(256) void k_fill(const int* __restrict__ src, const int* __restrict__ dst,
                                              const int* __restrict__ csr_off, int* __restrict__ fillcnt,
                                              int* __restrict__ csr_src){
    int e = blockIdx.x*256 + threadIdx.x;
    if(e < EE){
        int d = dst[e];
        int pos = csr_off[d] + atomicAdd(&fillcnt[d], 1);
        csr_src[pos] = src[e];
    }
}

// ---------- bf16 MFMA GEMM ----------
// C[M][192] = A[M][K] * Bt[192][K](bf16);  BM=64, BN=192, BK=32, 4 waves
// MODE 1: write bf16 C.  MODE 2: head-fused -> out[M][3] = gelu(C+bias) @ W2 + b2
template<int MODE, bool ABF16, bool BIAS>
__global__ __launch_bounds__(256) void k_gemm_mfma(const void* __restrict__ Av, const short* __restrict__ Bt,
                                                   const float* __restrict__ bias, void* __restrict__ Cv,
                                                   const float* __restrict__ W2, const float* __restrict__ b2,
                                                   int Mrows, int Kdim){
    __shared__ short As[64][40];
    __shared__ short Bs[192][40];
    int tid = threadIdx.x;
    int bm = blockIdx.x*64;
    int wv = tid>>6, lane = tid&63;
    int lm = lane&15, lq = lane>>4;

    f32x4 acc[12];
    #pragma unroll
    for(int i=0;i<12;i++) acc[i] = (f32x4){0.f,0.f,0.f,0.f};

    int ar = tid>>2, akg = (tid&3)<<3;
    bool aok = (bm + ar) < Mrows;
    const float*  ApF = (const float*)Av + (size_t)(bm + ar)*Kdim + akg;
    const ushort* ApB = (const ushort*)Av + (size_t)(bm + ar)*Kdim + akg;

    for(int k0 = 0; k0 < Kdim; k0 += 32){
        bf16x8 ap = {};
        if(ABF16){
            if(aok) ap = *(const bf16x8*)(ApB + k0);
        } else {
            float4 av0 = make_float4(0.f,0.f,0.f,0.f), av1 = av0;
            if(aok){
                av0 = *(const float4*)(ApF + k0);
                av1 = *(const float4*)(ApF + k0 + 4);
            }
            ap[0]=f2b(av0.x); ap[1]=f2b(av0.y); ap[2]=f2b(av0.z); ap[3]=f2b(av0.w);
            ap[4]=f2b(av1.x); ap[5]=f2b(av1.y); ap[6]=f2b(av1.z); ap[7]=f2b(av1.w);
        }
        bf16x8 bvals[3];
        #pragma unroll
        for(int i=0;i<3;i++){
            int idx = tid + i*256;
            int n = idx>>2, kg = (idx&3)<<3;
            bvals[i] = *(const bf16x8*)(Bt + (size_t)n*Kdim + k0 + kg);
        }
        __syncthreads();
        *(bf16x8*)&As[ar][akg] = ap;
        #pragma unroll
        for(int i=0;i<3;i++){
            int idx = tid + i*256;
            int n = idx>>2, kg = (idx&3)<<3;
            *(bf16x8*)&Bs[n][kg] = bvals[i];
        }
        __syncthreads();
        bf16x8 af = *(const bf16x8*)&As[wv*16 + lm][lq*8];
        #pragma unroll
        for(int ct=0; ct<12; ct++){
            bf16x8 bfr = *(const bf16x8*)&Bs[ct*16 + lm][lq*8];
            acc[ct] = __builtin_amdgcn_mfma_f32_16x16x32_bf16(af, bfr, acc[ct], 0, 0, 0);
        }
    }

    if(MODE == 1){
        short* C = (short*)Cv;
        #pragma unroll
        for(int ct=0; ct<12; ct++){
            int col = ct*16 + lm;
            float bs = BIAS ? bias[col] : 0.f;
            #pragma unroll
            for(int r=0; r<4; r++){
                int row = bm + wv*16 + lq*4 + r;
                if(row < Mrows) C[(size_t)row*HH + col] = f2b(acc[ct][r] + bs);
            }
        }
    } else {  // MODE 2: fused head
        float hs[4][3] = {};
        #pragma unroll
        for(int ct=0; ct<12; ct++){
            int col = ct*16 + lm;
            float bs = bias[col];
            float w20 = W2[col*3+0], w21 = W2[col*3+1], w22 = W2[col*3+2];
            #pragma unroll
            for(int r=0; r<4; r++){
                float g = gelu_exact(acc[ct][r] + bs);
                hs[r][0] += g*w20; hs[r][1] += g*w21; hs[r][2] += g*w22;
            }
        }
        #pragma unroll
        for(int off=1; off<16; off<<=1){
            #pragma unroll
            for(int r=0;r<4;r++){
                hs[r][0] += __shfl_xor(hs[r][0], off);
                hs[r][1] += __shfl_xor(hs[r][1], off);
                hs[r][2] += __shfl_xor(hs[r][2], off);
            }
        }
        if(lm == 0){
            float* O = (float*)Cv;
            #pragma unroll
            for(int r=0;r<4;r++){
                int row = bm + wv*16 + lq*4 + r;
                if(row < Mrows){
                    O[(size_t)row*3+0] = hs[r][0] + b2[0];
                    O[(size_t)row*3+1] = hs[r][1] + b2[1];
                    O[(size_t)row*3+2] = hs[r][2] + b2[2];
                }
            }
        }
    }
}

// ---------- GCN aggregation: bf16 gather, LDS-prefetched indices, 4-deep unroll ----------
__global__ __launch_bounds__(192) void k_agg(const ushort* __restrict__ hw, const int* __restrict__ csr_src,
                                             const int* __restrict__ csr_off, const float* __restrict__ deg,
                                             const float* __restrict__ dinv, const float* __restrict__ bias,
                                             float* __restrict__ out){
    __shared__ int   sidx[AGG_CH];
    __shared__ float swt [AGG_CH];
    int n = blockIdx.x;
    int t = threadIdx.x;                 // 0..191, features 2t, 2t+1
    float di = dinv[n];
    const ushort2* H2 = (const ushort2*)hw;
    ushort2 sv = H2[(size_t)n*192 + t];
    float self = di*di;
    float ax = b2f(sv.x)*self, ay = b2f(sv.y)*self;
    int beg = csr_off[n];
    int end = beg + (int)deg[n];
    for(int base = beg; base < end; base += AGG_CH){
        int m = min(AGG_CH, end - base);
        __syncthreads();
        for(int j = t; j < m; j += 192){
            int s = csr_src[base + j];
            sidx[j] = s;
            swt[j] = dinv[s]*di;
        }
        __syncthreads();
        int j = 0;
        for(; j+4 <= m; j += 4){
            int s0=sidx[j], s1=sidx[j+1], s2=sidx[j+2], s3=sidx[j+3];
            float w0=swt[j], w1=swt[j+1], w2=swt[j+2], w3=swt[j+3];
            ushort2 v0 = H2[(size_t)s0*192 + t];
            ushort2 v1 = H2[(size_t)s1*192 + t];
            ushort2 v2 = H2[(size_t)s2*192 + t];
            ushort2 v3 = H2[(size_t)s3*192 + t];
            ax += w0*b2f(v0.x) + w1*b2f(v1.x) + w2*b2f(v2.x) + w3*b2f(v3.x);
            ay += w0*b2f(v0.y) + w1*b2f(v1.y) + w2*b2f(v2.y) + w3*b2f(v3.y);
        }
        for(; j < m; j++){
            int s = sidx[j]; float ww = swt[j];
            ushort2 v = H2[(size_t)s*192 + t];
            ax += ww*b2f(v.x); ay += ww*b2f(v.y);
        }
    }
    int f = 2*t;
    int hh = (f < HH) ? f : f - HH;
    out[(size_t)n*FD + f]   = ax + bias[hh];
    out[(size_t)n*FD + f+1] = ay + bias[hh+1];
}

// ---------- GraphNorm: one stats pass (sum + sumsq), run-compressed atomics ----------
__global__ __launch_bounds__(384) void k_gn_stats(const float* __restrict__ h, const int* __restrict__ batch,
                                                  float* __restrict__ ssum, float* __restrict__ ssq){
    int f = threadIdx.x;
    int n0 = blockIdx.x*GN_CHUNK;
    int n1 = min(n0 + GN_CHUNK, NN);
    int g = batch[n0];
    float a = 0.f, a2 = 0.f;
    for(int n = n0; n < n1; n++){
        int gn = batch[n];
        if(gn != g){
            atomicAdd(&ssum[g*FD + f], a);
            atomicAdd(&ssq [g*FD + f], a2);
            a = 0.f; a2 = 0.f; g = gn;
        }
        float v = h[(size_t)n*FD + f];
        a += v; a2 += v*v;
    }
    atomicAdd(&ssum[g*FD + f], a);
    atomicAdd(&ssq [g*FD + f], a2);
}

// var = E[h^2] - (2a - a^2) * mean^2 ;  out = gelu(w*(h - a*mean)*rsqrt(var+eps)+b) (+res)
template<bool WF, bool WB, bool RES>
__global__ __launch_bounds__(384) void k_gn_final(const float* __restrict__ h, const int* __restrict__ batch,
                                                  const float* __restrict__ ssum, const float* __restrict__ ssq,
                                                  const float* __restrict__ cnt,
                                                  const float* __restrict__ w, const float* __restrict__ b,
                                                  const float* __restrict__ alpha,
                                                  const float* __restrict__ res,
                                                  float* __restrict__ outF, short* __restrict__ outB){
    int n = blockIdx.x;
    int f = threadIdx.x;
    int hh = (f < HH) ? f : f - HH;
    int g = batch[n];
    float a = alpha[hh];
    float ic = 1.0f / cnt[g];
    float mean = ssum[g*FD + f] * ic;
    float ex2  = ssq [g*FD + f] * ic;
    float var = ex2 - (2.0f*a - a*a)*mean*mean;
    float o = h[(size_t)n*FD + f];
    float v = w[hh]*(o - a*mean)*rsqrtf(var + EPS_GN) + b[hh];
    v = gelu_exact(v);
    if(RES) v += res[(size_t)n*FD + f];
    if(WF) outF[(size_t)n*FD + f] = v;
    if(WB) outB[(size_t)n*FD + f] = f2b(v);
}

extern "C" void kernel_launch(void* const* d_in, const int* in_sizes, int n_in,
                              void* d_out, int out_size, void* d_ws, size_t ws_size,
                              hipStream_t stream){
    const float* x     = (const float*)d_in[0];
    const int*   batch = (const int*)d_in[1];
    const int*   ei    = (const int*)d_in[2];
    const int*   src   = ei;
    const int*   dst   = ei + EE;
    const float* W0    = (const float*)d_in[3];
    const float* b0    = (const float*)d_in[4];
    const float* gn0_w = (const float*)d_in[5];
    const float* gn0_b = (const float*)d_in[6];
    const float* gn0_a = (const float*)d_in[7];
    const float* W1    = (const float*)d_in[8];
    const float* b1    = (const float*)d_in[9];
    const float* gn1_w = (const float*)d_in[10];
    const float* gn1_b = (const float*)d_in[11];
    const float* gn1_a = (const float*)d_in[12];
    const float* Wh1   = (const float*)d_in[13];
    const float* bh1   = (const float*)d_in[14];
    const float* Wh2   = (const float*)d_in[15];
    const float* bh2   = (const float*)d_in[16];
    float* out = (float*)d_out;

    char* w = (char*)d_ws;
    auto alloc = [&](size_t bytes)->void*{
        void* p = (void*)w;
        w += (bytes + 255) & ~(size_t)255;
        return p;
    };
    char* zbase = w;
    float* deg     = (float*)alloc((size_t)NN*4);
    int*   fillcnt = (int*)  alloc((size_t)NN*4);
    int*   partial = (int*)  alloc(256*4);
    float* s0m     = (float*)alloc((size_t)GG*FD*4);
    float* s0q     = (float*)alloc((size_t)GG*FD*4);
    float* s1m     = (float*)alloc((size_t)GG*FD*4);
    float* s1q     = (float*)alloc((size_t)GG*FD*4);
    size_t zbytes = (size_t)(w - zbase);
    float* cnt     = (float*)alloc((size_t)GG*4);
    float* dinv    = (float*)alloc((size_t)NN*4);
    int*   csr_off = (int*)  alloc((size_t)NN*4);
    int*   csr_src = (int*)  alloc((size_t)EE*4);
    short* Wt0     = (short*)alloc((size_t)HH*CC*2);
    short* Wt1     = (short*)alloc((size_t)HH*HH*2);
    short* Wth1    = (short*)alloc((size_t)HH*HH*2);
    short* hb0     = (short*)alloc((size_t)MR*HH*2);   // bf16 feature bufs
    short* hb1     = (short*)alloc((size_t)MR*HH*2);
    float* agg0    = (float*)alloc((size_t)MR*HH*4);   // fp32 agg / gn bufs
    float* agg1    = (float*)alloc((size_t)MR*HH*4);

    hipMemsetAsync(zbase, 0, zbytes, stream);

    k_deg  <<<(EE+255)/256, 256, 0, stream>>>(dst, deg);
    k_cnt2 <<<1, 64, 0, stream>>>(batch, cnt);
    k_dinv <<<(NN+255)/256, 256, 0, stream>>>(deg, dinv);
    k_wconv<<<(CC*HH+255)/256, 256, 0, stream>>>(W0, W1, Wh1, Wt0, Wt1, Wth1);

    int nscan = (NN+255)/256;
    k_scan1<<<nscan, 256, 0, stream>>>(deg, partial);
    k_scan2<<<1,     256, 0, stream>>>(partial);
    k_scan3<<<nscan, 256, 0, stream>>>(deg, partial, csr_off);
    k_fill <<<(EE+255)/256, 256, 0, stream>>>(src, dst, csr_off, fillcnt, csr_src);

    int gemm_grid = (MR+63)/64;
    int ngn = (NN + GN_CHUNK - 1)/GN_CHUNK;

    // layer 0: 768 -> 192
    k_gemm_mfma<1,false,false><<<gemm_grid, 256, 0, stream>>>(x, Wt0, nullptr, hb0, nullptr, nullptr, MR, CC);
    k_agg<<<NN, 192, 0, stream>>>((const ushort*)hb0, csr_src, csr_off, deg, dinv, b0, agg0);
    k_gn_stats<<<ngn, 384, 0, stream>>>(agg0, batch, s0m, s0q);
    k_gn_final<true,true,false><<<NN, 384, 0, stream>>>(agg0, batch, s0m, s0q, cnt, gn0_w, gn0_b, gn0_a,
                                                        nullptr, agg0, hb0);

    // layer 1: 192 -> 192 + residual
    k_gemm_mfma<1,true,false><<<gemm_grid, 256, 0, stream>>>(hb0, Wt1, nullptr, hb1, nullptr, nullptr, MR, HH);
    k_agg<<<NN, 192, 0, stream>>>((const ushort*)hb1, csr_src, csr_off, deg, dinv, b1, agg1);
    k_gn_stats<<<ngn, 384, 0, stream>>>(agg1, batch, s1m, s1q);
    k_gn_final<false,true,true><<<NN, 384, 0, stream>>>(agg1, batch, s1m, s1q, cnt, gn1_w, gn1_b, gn1_a,
                                                        agg0, nullptr, hb1);

    // fused head: gelu(h@Wh1+bh1) @ Wh2 + bh2 -> out
    k_gemm_mfma<2,true,true><<<gemm_grid, 256, 0, stream>>>(hb1, Wth1, bh1, out, Wh2, bh2, MR, HH);
}